// Round 3
// baseline (92.523 us; speedup 1.0000x reference)
//
#include <hip/hip_runtime.h>

constexpr int DEPTH      = 10;
constexpr int NUM_TREES  = 64;
constexpr int BATCH      = 2048;
constexpr int NUM_FORKS  = (1 << DEPTH) - 1;   // 1023
constexpr int PAIRS      = BATCH * NUM_TREES;  // 131072
constexpr int WPB        = 4;                  // waves (=pairs) per block

constexpr float LOG2E = 1.44269504088896340736f;

// Granule-preserving XOR swizzle: dword index d -> d ^ (((d>>5)&7)<<2).
// Bits [1:0] untouched (16B granules stay contiguous -> b128 writes legal);
// bijective within each 32-dword (128B) window.
__device__ __forceinline__ float ldsw(const float* sb, int d) {
    return sb[d ^ ((d >> 3) & 28)];
}

__global__ __launch_bounds__(256, 4) void ndt_kernel(const float* __restrict__ x,
                                                     float* __restrict__ out) {
    __shared__ __align__(16) float sb[4096];   // 4 rows x 1023, packed; padded to full window
    const int tid  = threadIdx.x;
    const int wave = tid >> 6;
    const int lane = tid & 63;
    const int pair = blockIdx.x * WPB + wave;

    // Block-wide staging: 4 rows = 4092 dwords = 1023 float4s, 16B-aligned
    // (blockIdx.x * 16368 bytes). global_load_dwordx4, ds_write_b128 (swizzled,
    // conflict-free: granule' mod 8 is a permutation within each 8-lane group).
    const float4* __restrict__ gv =
        reinterpret_cast<const float4*>(x + (size_t)blockIdx.x * (WPB * NUM_FORKS));
    #pragma unroll
    for (int k = 0; k < 4; ++k) {
        int idx = tid + (k << 8);
        if (idx < 1023) {
            float4 v = gv[idx];
            int d = idx << 2;
            *reinterpret_cast<float4*>(&sb[d ^ ((d >> 3) & 28)]) = v;
        }
    }
    __syncthreads();

    const int W = wave * NUM_FORKS;   // this wave's row base (pre-swizzle dword index)

    // ---- levels 9..7 in rational form: subtree value = N/D, one rcp at v7 ----
    float E9[8], D9[8];
    {
        const int d0 = W + 511 + (lane << 3);
        #pragma unroll
        for (int c = 0; c < 8; ++c) {
            float xv = ldsw(sb, d0 + c);
            E9[c] = __builtin_amdgcn_exp2f(-LOG2E * xv);
            D9[c] = 1.0f + E9[c];
        }
    }
    float N8[4], D8[4];
    {
        const int d0 = W + 255 + (lane << 2);
        #pragma unroll
        for (int dd = 0; dd < 4; ++dd) {
            float xv = ldsw(sb, d0 + dd);
            float E8 = __builtin_amdgcn_exp2f(-LOG2E * xv);
            N8[dd] = fmaf(E8, D9[2 * dd + 1], D9[2 * dd]);
            D8[dd] = D9[2 * dd] * D9[2 * dd + 1] * (1.0f + E8);
        }
    }
    float v7[2];
    {
        const int d0 = W + 127 + (lane << 1);
        #pragma unroll
        for (int e = 0; e < 2; ++e) {
            float E7 = __builtin_amdgcn_exp2f(-LOG2E * ldsw(sb, d0 + e));
            float N7 = fmaf(E7 * N8[2 * e], D8[2 * e + 1], N8[2 * e + 1] * D8[2 * e]);
            float D7 = D8[2 * e] * D8[2 * e + 1] * (1.0f + E7);
            v7[e] = N7 * __builtin_amdgcn_rcpf(D7);
        }
    }

    // ---- level 6 ----
    float E6 = __builtin_amdgcn_exp2f(-LOG2E * ldsw(sb, W + 63 + lane));
    float s6 = __builtin_amdgcn_rcpf(1.0f + E6);
    float v6 = fmaf(s6, v7[1] - v7[0], v7[0]);

    // ---- path prefix levels 0..5: prefix = rcp( prod(1 + 2^{+-u_i}) ) ----
    float p = 1.0f;
    #pragma unroll
    for (int i = 0; i < 6; ++i) {
        int a = lane >> (6 - i);          // ancestor index at level i
        int b = (lane >> (5 - i)) & 1;    // child bit taken at level i
        float u = LOG2E * ldsw(sb, W + (1 << i) - 1 + a);
        float wv = __builtin_amdgcn_exp2f(b ? -u : u);
        p *= (1.0f + wv);
    }
    float v = v6 * __builtin_amdgcn_rcpf(p);

    // ---- wave-wide sum ----
    #pragma unroll
    for (int off = 32; off > 0; off >>= 1) v += __shfl_xor(v, off, 64);
    if (lane == 0) out[pair] = v;
}

extern "C" void kernel_launch(void* const* d_in, const int* in_sizes, int n_in,
                              void* d_out, int out_size, void* d_ws, size_t ws_size,
                              hipStream_t stream) {
    const float* x = (const float*)d_in[0];
    float* out = (float*)d_out;
    dim3 grid(PAIRS / WPB), block(WPB * 64);
    ndt_kernel<<<grid, block, 0, stream>>>(x, out);
}

// Round 4
// 90.924 us; speedup vs baseline: 1.0176x; 1.0176x over previous
//
#include <hip/hip_runtime.h>

constexpr int DEPTH      = 10;
constexpr int NUM_TREES  = 64;
constexpr int BATCH      = 2048;
constexpr int NUM_FORKS  = (1 << DEPTH) - 1;   // 1023
constexpr int PAIRS      = BATCH * NUM_TREES;  // 131072
constexpr int WPB        = 4;                  // waves (=pairs) per block

constexpr float LOG2E = 1.44269504088896340736f;

__global__ __launch_bounds__(256, 4) void ndt_kernel(const float* __restrict__ x,
                                                     float* __restrict__ out) {
    const int tid  = threadIdx.x;
    const int wave = tid >> 6;
    const int lane = tid & 63;
    const int pair = blockIdx.x * WPB + wave;          // pair = b*64 + t
    const float* __restrict__ xp = x + (size_t)pair * NUM_FORKS;

    // ---- issue ALL global reads up front (no LDS, L1 handles redistribution).
    // Leaves: wave spans a contiguous 2KB; each 64B line fetched once, the
    // stride-8 iterations re-hit it in L1. Levels 0..5 are (near-)broadcast.
    float xs9[8];
    #pragma unroll
    for (int c = 0; c < 8; ++c) xs9[c] = xp[511 + 8 * lane + c];
    float xs8[4];
    #pragma unroll
    for (int d = 0; d < 4; ++d) xs8[d] = xp[255 + 4 * lane + d];
    float xs7[2];
    #pragma unroll
    for (int e = 0; e < 2; ++e) xs7[e] = xp[127 + 2 * lane + e];
    float xs6 = xp[63 + lane];
    float xsp[6];
    #pragma unroll
    for (int i = 0; i < 6; ++i) xsp[i] = xp[(1 << i) - 1 + (lane >> (6 - i))];

    // ---- levels 9..7 in rational form: subtree value = N/D, one rcp at v7 ----
    float E9[8], D9[8];
    #pragma unroll
    for (int c = 0; c < 8; ++c) {
        E9[c] = __builtin_amdgcn_exp2f(-LOG2E * xs9[c]);
        D9[c] = 1.0f + E9[c];
    }
    float N8[4], D8[4];
    #pragma unroll
    for (int d = 0; d < 4; ++d) {
        float E8 = __builtin_amdgcn_exp2f(-LOG2E * xs8[d]);
        N8[d] = fmaf(E8, D9[2 * d + 1], D9[2 * d]);
        D8[d] = D9[2 * d] * D9[2 * d + 1] * (1.0f + E8);
    }
    float v7[2];
    #pragma unroll
    for (int e = 0; e < 2; ++e) {
        float E7 = __builtin_amdgcn_exp2f(-LOG2E * xs7[e]);
        float N7 = fmaf(E7 * N8[2 * e], D8[2 * e + 1], N8[2 * e + 1] * D8[2 * e]);
        float D7 = D8[2 * e] * D8[2 * e + 1] * (1.0f + E7);
        v7[e] = N7 * __builtin_amdgcn_rcpf(D7);
    }

    // ---- level 6 ----
    float E6 = __builtin_amdgcn_exp2f(-LOG2E * xs6);
    float s6 = __builtin_amdgcn_rcpf(1.0f + E6);
    float v6 = fmaf(s6, v7[1] - v7[0], v7[0]);

    // ---- path prefix levels 0..5: prefix = rcp( prod(1 + 2^{+-u_i}) ) ----
    float p = 1.0f;
    #pragma unroll
    for (int i = 0; i < 6; ++i) {
        int b = (lane >> (5 - i)) & 1;    // child bit taken at level i
        float u = LOG2E * xsp[i];
        float w = __builtin_amdgcn_exp2f(b ? -u : u);   // b=1 -> sigma path; b=0 -> 1-sigma path
        p *= (1.0f + w);
    }
    float v = v6 * __builtin_amdgcn_rcpf(p);

    // ---- wave-wide sum ----
    #pragma unroll
    for (int off = 32; off > 0; off >>= 1) v += __shfl_xor(v, off, 64);
    if (lane == 0) out[pair] = v;
}

extern "C" void kernel_launch(void* const* d_in, const int* in_sizes, int n_in,
                              void* d_out, int out_size, void* d_ws, size_t ws_size,
                              hipStream_t stream) {
    const float* x = (const float*)d_in[0];
    float* out = (float*)d_out;
    dim3 grid(PAIRS / WPB), block(WPB * 64);
    ndt_kernel<<<grid, block, 0, stream>>>(x, out);
}

// Round 5
// 90.251 us; speedup vs baseline: 1.0252x; 1.0075x over previous
//
#include <hip/hip_runtime.h>

constexpr int DEPTH      = 10;
constexpr int NUM_TREES  = 64;
constexpr int BATCH      = 2048;
constexpr int NUM_FORKS  = (1 << DEPTH) - 1;   // 1023
constexpr int PAIRS      = BATCH * NUM_TREES;  // 131072
constexpr int WPB        = 4;                  // waves per block
constexpr int REGION     = 1056;               // dword stride per wave LDS region

__device__ __forceinline__ float sig(float v) {
    // fast sigmoid: 1/(1+exp(-v)); exp->v_exp_f32, rcp->v_rcp_f32
    return __builtin_amdgcn_rcpf(1.0f + __expf(-v));
}

__global__ __launch_bounds__(256, 4) void ndt_kernel(const float* __restrict__ x,
                                                     float* __restrict__ out) {
    __shared__ float lds[WPB * REGION + 8];
    const int tid  = threadIdx.x;
    const int wave = tid >> 6;
    const int lane = tid & 63;
    const int pair = blockIdx.x * WPB + wave;          // pair = b*64 + t
    const float* __restrict__ xp = x + (size_t)pair * NUM_FORKS;

    // s[q] = x[q-1]; +4/+1 dword shift keeps s[512+8*lane] and s[256+4*lane]
    // 16B-aligned so leaf/level-8 reads stay ds_read_b128.
    float* s = &lds[wave * REGION + 4];

    // stage 1023 floats, coalesced b32, stride-1 LDS writes (conflict-free)
    #pragma unroll
    for (int m = 0; m < 16; ++m) {
        int f = m * 64 + lane;
        if (m < 15 || f < NUM_FORKS) s[1 + f] = xp[f];
    }
    // Each wave reads only its own LDS region; DS ops are in-order per wave.
    // Fence compiler motion only (no block barrier -> waves stay decoupled).
    __builtin_amdgcn_wave_barrier();

    // ---- level 9: leaf sigmoids (8 per lane, 2x ds_read_b128) ----
    float t9[8];
    #pragma unroll
    for (int c = 0; c < 8; ++c) t9[c] = sig(s[512 + 8 * lane + c]);

    // ---- level 8: v8[d] = (1-s)*t9[2d] + s*t9[2d+1] ----
    float v8[4];
    #pragma unroll
    for (int d = 0; d < 4; ++d) {
        float sg = sig(s[256 + 4 * lane + d]);
        v8[d] = fmaf(sg, t9[2 * d + 1] - t9[2 * d], t9[2 * d]);
    }

    // ---- level 7 ----
    float v7[2];
    #pragma unroll
    for (int e = 0; e < 2; ++e) {
        float sg = sig(s[128 + 2 * lane + e]);
        v7[e] = fmaf(sg, v8[2 * e + 1] - v8[2 * e], v8[2 * e]);
    }

    // ---- level 6 ----
    float s6 = sig(s[64 + lane]);
    float v6 = fmaf(s6, v7[1] - v7[0], v7[0]);

    // ---- path prefix over levels 0..5 (broadcast-friendly reads) ----
    float prefix = 1.0f;
    #pragma unroll
    for (int i = 0; i < 6; ++i) {
        int a = lane >> (6 - i);          // ancestor index at level i
        int b = (lane >> (5 - i)) & 1;    // child bit taken at level i
        float sg = sig(s[(1 << i) + a]);
        prefix *= b ? sg : (1.0f - sg);
    }

    // ---- combine + wave-wide sum ----
    float v = prefix * v6;
    #pragma unroll
    for (int off = 32; off > 0; off >>= 1) v += __shfl_xor(v, off, 64);
    if (lane == 0) out[pair] = v;
}

extern "C" void kernel_launch(void* const* d_in, const int* in_sizes, int n_in,
                              void* d_out, int out_size, void* d_ws, size_t ws_size,
                              hipStream_t stream) {
    const float* x = (const float*)d_in[0];
    float* out = (float*)d_out;
    dim3 grid(PAIRS / WPB), block(WPB * 64);
    ndt_kernel<<<grid, block, 0, stream>>>(x, out);
}